// Round 3
// baseline (339.807 us; speedup 1.0000x reference)
//
#include <hip/hip_runtime.h>
#include <hip/hip_bf16.h>
#include <stdint.h>

#define RING 4
#define BATCH 2
#define SEQ 8192
#define CHUNK 2048
#define HIDDEN 2048
#define G91 91

typedef unsigned short u16;
typedef __bf16 bf16x8 __attribute__((ext_vector_type(8)));
typedef float f32x4 __attribute__((ext_vector_type(4)));

// Boustrophedon mapping: mapping[pos] = row*91 + (row odd ? 90-col : col).
// For p < 2048 the image is exactly [0,2048) (rank-0 chunk = whole snake rows).
__device__ __forceinline__ int hmap(int p) {
    int row = p / G91;
    int col = p - row * G91;
    return row * G91 + ((row & 1) ? (G91 - 1 - col) : col);
}

__device__ __forceinline__ u16 f2bf(float f) {  // RNE float->bf16
    unsigned int u = __float_as_uint(f);
    u = u + 0x7fffu + ((u >> 16) & 1u);
    return (u16)(u >> 16);
}

// ---------------- zero rows [CHUNK, SEQ) of both batches ----------------
__global__ __launch_bounds__(256) void zero_tail(float4* __restrict__ out4) {
    const int per_batch = (SEQ - CHUNK) * (HIDDEN / 4);  // 3,145,728
    int idx = blockIdx.x * 256 + threadIdx.x;            // grid sized exactly
    int b = idx >= per_batch;
    int within = idx - b * per_batch;
    long base = ((long)b * SEQ + CHUNK) * (HIDDEN / 4);
    out4[base + within] = make_float4(0.f, 0.f, 0.f, 0.f);
}

// ---- P[b,i,j] = sum_r softmax_j(scores[r,b,i,:] * 1/sqrt(128)), bf16 ----
__global__ __launch_bounds__(256) void softmax_sum(const float* __restrict__ scores,
                                                   u16* __restrict__ P) {
    const float scale = 0.08838834764831845f;  // 1/sqrt(128)
    int bi = blockIdx.x;        // 0..4095
    int b = bi >> 11;
    int i = bi & (CHUNK - 1);
    int t = threadIdx.x;
    int w = t >> 6, lane = t & 63;

    float4 v[RING][2];
#pragma unroll
    for (int r = 0; r < RING; ++r) {
        const float4* src = (const float4*)scores +
            ((((long)(r * BATCH + b) * CHUNK + i) * CHUNK) >> 2);
        v[r][0] = src[t];          // j = t*4 .. t*4+3
        v[r][1] = src[t + 256];    // j = 1024 + t*4 ..
    }
    float* pv = (float*)v;
#pragma unroll
    for (int q = 0; q < RING * 8; ++q) pv[q] *= scale;

    // block max per r
    float lm[RING];
#pragma unroll
    for (int r = 0; r < RING; ++r) {
        float* a = (float*)&v[r][0];
        float m0 = fmaxf(fmaxf(a[0], a[1]), fmaxf(a[2], a[3]));
        float m1 = fmaxf(fmaxf(a[4], a[5]), fmaxf(a[6], a[7]));
        lm[r] = fmaxf(m0, m1);
    }
#pragma unroll
    for (int off = 32; off >= 1; off >>= 1)
#pragma unroll
        for (int r = 0; r < RING; ++r)
            lm[r] = fmaxf(lm[r], __shfl_xor(lm[r], off, 64));
    __shared__ float red[4][RING];
    if (lane == 0) {
#pragma unroll
        for (int r = 0; r < RING; ++r) red[w][r] = lm[r];
    }
    __syncthreads();
    float m[RING];
#pragma unroll
    for (int r = 0; r < RING; ++r)
        m[r] = fmaxf(fmaxf(red[0][r], red[1][r]), fmaxf(red[2][r], red[3][r]));
    __syncthreads();  // before red reuse

    // exp + block sum per r
    float e[RING][8];
    float ls[RING];
#pragma unroll
    for (int r = 0; r < RING; ++r) {
        float* a = (float*)&v[r][0];
        ls[r] = 0.f;
#pragma unroll
        for (int q = 0; q < 8; ++q) {
            e[r][q] = __expf(a[q] - m[r]);
            ls[r] += e[r][q];
        }
    }
#pragma unroll
    for (int off = 32; off >= 1; off >>= 1)
#pragma unroll
        for (int r = 0; r < RING; ++r)
            ls[r] += __shfl_xor(ls[r], off, 64);
    if (lane == 0) {
#pragma unroll
        for (int r = 0; r < RING; ++r) red[w][r] = ls[r];
    }
    __syncthreads();
    float zi[RING];
#pragma unroll
    for (int r = 0; r < RING; ++r)
        zi[r] = 1.0f / (red[0][r] + red[1][r] + red[2][r] + red[3][r]);

    float p[8];
#pragma unroll
    for (int q = 0; q < 8; ++q)
        p[q] = e[0][q] * zi[0] + e[1][q] * zi[1] + e[2][q] * zi[2] + e[3][q] * zi[3];

    u16* dst = P + ((long)b * CHUNK + i) * CHUNK;
    *(uint2*)(dst + t * 4) = make_uint2(
        (unsigned)f2bf(p[0]) | ((unsigned)f2bf(p[1]) << 16),
        (unsigned)f2bf(p[2]) | ((unsigned)f2bf(p[3]) << 16));
    *(uint2*)(dst + 1024 + t * 4) = make_uint2(
        (unsigned)f2bf(p[4]) | ((unsigned)f2bf(p[5]) << 16),
        (unsigned)f2bf(p[6]) | ((unsigned)f2bf(p[7]) << 16));
}

// ---- xlT[b,d,j] = bf16(x[b, hmap(j), d])  (transposed gather via LDS) ----
__global__ __launch_bounds__(256) void gather_transpose(const float* __restrict__ x,
                                                        u16* __restrict__ xlT) {
    __shared__ u16 lt[64][72];  // [d][j], pad to 144B stride (16B-aligned rows)
    int blk = blockIdx.x;       // 0..2047
    int b = blk >> 10;
    int tile = blk & 1023;
    int j0 = (tile >> 5) << 6;
    int d0 = (tile & 31) << 6;
    int t = threadIdx.x;
    int jr = t >> 2;   // 0..63
    int dq = t & 3;
    int srow = hmap(j0 + jr);
    const float4* src = (const float4*)(x + ((long)b * SEQ + srow) * HIDDEN + d0) + dq * 4;
#pragma unroll
    for (int q = 0; q < 4; ++q) {
        float4 vv = src[q];
        int dd = dq * 16 + q * 4;
        lt[dd + 0][jr] = f2bf(vv.x);
        lt[dd + 1][jr] = f2bf(vv.y);
        lt[dd + 2][jr] = f2bf(vv.z);
        lt[dd + 3][jr] = f2bf(vv.w);
    }
    __syncthreads();
    int d = t >> 2;
    int jb = (t & 3) * 16;
    u16* dst = xlT + ((long)b * HIDDEN + d0 + d) * CHUNK + j0 + jb;
    uint4 w0 = *(const uint4*)&lt[d][jb];
    uint4 w1 = *(const uint4*)&lt[d][jb + 8];
    *(uint4*)dst = w0;
    *((uint4*)(dst + 8)) = w1;
}

// ---- C[b] = P[b] @ xlT[b]^T, scattered: out[b, hmap(i), n] = C[i][n] ----
// 128x128 tile, 4 waves, BK=64, global_load_lds(16B) staging,
// XOR-swizzled LDS (slot = row*8 + (kb ^ (row&7))) on both stage-src and read.
__global__ __launch_bounds__(256) void gemm_scatter(const u16* __restrict__ P,
                                                    const u16* __restrict__ xlT,
                                                    float* __restrict__ out) {
    __shared__ u16 As[128 * 64];
    __shared__ u16 Bs[128 * 64];
    int blk = blockIdx.x;
    int b = blk >> 8;
    int tl = blk & 255;
    int ti = tl >> 4, tj = tl & 15;
    const int i0 = ti << 7, n0 = tj << 7;
    const u16* A = P + (long)b * CHUNK * CHUNK;
    const u16* B = xlT + (long)b * HIDDEN * CHUNK;
    int t = threadIdx.x, w = t >> 6, lane = t & 63;
    int wr = w >> 1, wc = w & 1;
    int srow = lane >> 3;              // row within 8-row stage segment
    int skb = (lane & 7) ^ srow;       // logical kb this lane fetches (inverse swizzle)

    f32x4 z = {0.f, 0.f, 0.f, 0.f};
    f32x4 acc[4][4];
#pragma unroll
    for (int m = 0; m < 4; ++m)
#pragma unroll
        for (int n = 0; n < 4; ++n) acc[m][n] = z;

    for (int k0 = 0; k0 < CHUNK; k0 += 64) {
        __syncthreads();  // previous tile fully consumed
#pragma unroll
        for (int seg = 0; seg < 4; ++seg) {
            int q = (w << 2) + seg;         // stage instruction id 0..15
            int grow = (q << 3) + srow;     // tile row 0..127
            const u16* ga = A + (long)(i0 + grow) * CHUNK + k0 + (skb << 3);
            const u16* gb = B + (long)(n0 + grow) * CHUNK + k0 + (skb << 3);
            __builtin_amdgcn_global_load_lds(
                (const __attribute__((address_space(1))) void*)ga,
                (__attribute__((address_space(3))) void*)(As + (q << 9)), 16, 0, 0);
            __builtin_amdgcn_global_load_lds(
                (const __attribute__((address_space(1))) void*)gb,
                (__attribute__((address_space(3))) void*)(Bs + (q << 9)), 16, 0, 0);
        }
        __syncthreads();  // drains vmcnt before reads
#pragma unroll
        for (int ks = 0; ks < 2; ++ks) {
            int kb = (ks << 2) + (lane >> 4);
            bf16x8 fa[4], fb[4];
#pragma unroll
            for (int m = 0; m < 4; ++m) {
                int row = (wr << 6) + (m << 4) + (lane & 15);
                int phys = (row << 3) + (kb ^ (row & 7));
                fa[m] = *(const bf16x8*)(As + (phys << 3));
            }
#pragma unroll
            for (int n = 0; n < 4; ++n) {
                int row = (wc << 6) + (n << 4) + (lane & 15);
                int phys = (row << 3) + (kb ^ (row & 7));
                fb[n] = *(const bf16x8*)(Bs + (phys << 3));
            }
#pragma unroll
            for (int m = 0; m < 4; ++m)
#pragma unroll
                for (int n = 0; n < 4; ++n)
                    acc[m][n] = __builtin_amdgcn_mfma_f32_16x16x32_bf16(
                        fa[m], fb[n], acc[m][n], 0, 0, 0);
        }
    }

    // epilogue: C/D layout col=lane&15, row=(lane>>4)*4+r  [m89]
    int cr = (lane >> 4) << 2;
    int cc = lane & 15;
#pragma unroll
    for (int m = 0; m < 4; ++m) {
#pragma unroll
        for (int r = 0; r < 4; ++r) {
            int i = i0 + (wr << 6) + (m << 4) + cr + r;
            int orow = hmap(i);  // scatter row (stays < 2048)
            float* op = out + ((long)b * SEQ + orow) * HIDDEN + n0 + (wc << 6) + cc;
#pragma unroll
            for (int n = 0; n < 4; ++n) op[n << 4] = acc[m][n][r];
        }
    }
}

extern "C" void kernel_launch(void* const* d_in, const int* in_sizes, int n_in,
                              void* d_out, int out_size, void* d_ws, size_t ws_size,
                              hipStream_t stream) {
    const float* x = (const float*)d_in[0];
    const float* scores = (const float*)d_in[1];
    float* out = (float*)d_out;

    const size_t elems = (size_t)BATCH * CHUNK * CHUNK;  // u16 elements per buffer
    u16 *Pp, *xlT;
    if (ws_size >= 2 * elems * sizeof(u16)) {
        Pp = (u16*)d_ws;
        xlT = (u16*)d_ws + elems;
    } else {
        // stash in out's zero-tail (batch-0 rows [2048,6144)); zero_tail runs last
        Pp = (u16*)(out + (size_t)CHUNK * HIDDEN);
        xlT = (u16*)(out + (size_t)2 * CHUNK * HIDDEN);
    }

    softmax_sum<<<BATCH * CHUNK, 256, 0, stream>>>(scores, Pp);
    gather_transpose<<<2048, 256, 0, stream>>>(x, xlT);
    gemm_scatter<<<BATCH * 256, 256, 0, stream>>>(Pp, xlT, out);
    zero_tail<<<(BATCH * (SEQ - CHUNK) * (HIDDEN / 4)) / 256, 256, 0, stream>>>((float4*)out);
}

// Round 6
// 334.910 us; speedup vs baseline: 1.0146x; 1.0146x over previous
//
#include <hip/hip_runtime.h>
#include <hip/hip_bf16.h>
#include <stdint.h>

#define RING 4
#define BATCH 2
#define SEQ 8192
#define CHUNK 2048
#define HIDDEN 2048
#define G91 91

typedef unsigned short u16;
typedef __bf16 bf16x8 __attribute__((ext_vector_type(8)));
typedef float f32x4 __attribute__((ext_vector_type(4)));

// Boustrophedon mapping: mapping[pos] = row*91 + (row odd ? 90-col : col).
// For p < 2048 the image is exactly [0,2048) (rank-0 chunk = whole snake rows).
__device__ __forceinline__ int hmap(int p) {
    int row = p / G91;
    int col = p - row * G91;
    return row * G91 + ((row & 1) ? (G91 - 1 - col) : col);
}

__device__ __forceinline__ u16 f2bf(float f) {  // RNE float->bf16
    unsigned int u = __float_as_uint(f);
    u = u + 0x7fffu + ((u >> 16) & 1u);
    return (u16)(u >> 16);
}

// ---------------- fallback: zero rows [CHUNK, SEQ) of both batches ----------------
__global__ __launch_bounds__(256) void zero_tail(float4* __restrict__ out4) {
    const int per_batch = (SEQ - CHUNK) * (HIDDEN / 4);  // 3,145,728
    int idx = blockIdx.x * 256 + threadIdx.x;
    int b = idx >= per_batch;
    int within = idx - b * per_batch;
    long base = ((long)b * SEQ + CHUNK) * (HIDDEN / 4);
    out4[base + within] = make_float4(0.f, 0.f, 0.f, 0.f);
}

// ---- P[b,i,j] = sum_r softmax_j(scores[r,b,i,:] * 1/sqrt(128)), bf16 ----
__global__ __launch_bounds__(256) void softmax_sum(const float* __restrict__ scores,
                                                   u16* __restrict__ P) {
    const float scale = 0.08838834764831845f;  // 1/sqrt(128)
    int bi = blockIdx.x;        // 0..4095
    int b = bi >> 11;
    int i = bi & (CHUNK - 1);
    int t = threadIdx.x;
    int w = t >> 6, lane = t & 63;

    float4 v[RING][2];
#pragma unroll
    for (int r = 0; r < RING; ++r) {
        const float4* src = (const float4*)scores +
            ((((long)(r * BATCH + b) * CHUNK + i) * CHUNK) >> 2);
        v[r][0] = src[t];          // j = t*4 .. t*4+3
        v[r][1] = src[t + 256];    // j = 1024 + t*4 ..
    }
    float* pv = (float*)v;
#pragma unroll
    for (int q = 0; q < RING * 8; ++q) pv[q] *= scale;

    float lm[RING];
#pragma unroll
    for (int r = 0; r < RING; ++r) {
        float* a = (float*)&v[r][0];
        float m0 = fmaxf(fmaxf(a[0], a[1]), fmaxf(a[2], a[3]));
        float m1 = fmaxf(fmaxf(a[4], a[5]), fmaxf(a[6], a[7]));
        lm[r] = fmaxf(m0, m1);
    }
#pragma unroll
    for (int off = 32; off >= 1; off >>= 1)
#pragma unroll
        for (int r = 0; r < RING; ++r)
            lm[r] = fmaxf(lm[r], __shfl_xor(lm[r], off, 64));
    __shared__ float red[4][RING];
    if (lane == 0) {
#pragma unroll
        for (int r = 0; r < RING; ++r) red[w][r] = lm[r];
    }
    __syncthreads();
    float m[RING];
#pragma unroll
    for (int r = 0; r < RING; ++r)
        m[r] = fmaxf(fmaxf(red[0][r], red[1][r]), fmaxf(red[2][r], red[3][r]));
    __syncthreads();  // before red reuse

    float e[RING][8];
    float ls[RING];
#pragma unroll
    for (int r = 0; r < RING; ++r) {
        float* a = (float*)&v[r][0];
        ls[r] = 0.f;
#pragma unroll
        for (int q = 0; q < 8; ++q) {
            e[r][q] = __expf(a[q] - m[r]);
            ls[r] += e[r][q];
        }
    }
#pragma unroll
    for (int off = 32; off >= 1; off >>= 1)
#pragma unroll
        for (int r = 0; r < RING; ++r)
            ls[r] += __shfl_xor(ls[r], off, 64);
    if (lane == 0) {
#pragma unroll
        for (int r = 0; r < RING; ++r) red[w][r] = ls[r];
    }
    __syncthreads();
    float zi[RING];
#pragma unroll
    for (int r = 0; r < RING; ++r)
        zi[r] = 1.0f / (red[0][r] + red[1][r] + red[2][r] + red[3][r]);

    float p[8];
#pragma unroll
    for (int q = 0; q < 8; ++q)
        p[q] = e[0][q] * zi[0] + e[1][q] * zi[1] + e[2][q] * zi[2] + e[3][q] * zi[3];

    u16* dst = P + ((long)b * CHUNK + i) * CHUNK;
    *(uint2*)(dst + t * 4) = make_uint2(
        (unsigned)f2bf(p[0]) | ((unsigned)f2bf(p[1]) << 16),
        (unsigned)f2bf(p[2]) | ((unsigned)f2bf(p[3]) << 16));
    *(uint2*)(dst + 1024 + t * 4) = make_uint2(
        (unsigned)f2bf(p[4]) | ((unsigned)f2bf(p[5]) << 16),
        (unsigned)f2bf(p[6]) | ((unsigned)f2bf(p[7]) << 16));
}

// ---- xlT[b,d,j] = bf16(x[b, hmap(j), d])  (transposed gather via LDS) ----
__global__ __launch_bounds__(256) void gather_transpose(const float* __restrict__ x,
                                                        u16* __restrict__ xlT) {
    __shared__ u16 lt[64][72];  // [d][j], pad to 144B stride (16B-aligned rows)
    int blk = blockIdx.x;       // 0..2047
    int b = blk >> 10;
    int tile = blk & 1023;
    int j0 = (tile >> 5) << 6;
    int d0 = (tile & 31) << 6;
    int t = threadIdx.x;
    int jr = t >> 2;   // 0..63
    int dq = t & 3;
    int srow = hmap(j0 + jr);
    const float4* src = (const float4*)(x + ((long)b * SEQ + srow) * HIDDEN + d0) + dq * 4;
#pragma unroll
    for (int q = 0; q < 4; ++q) {
        float4 vv = src[q];
        int dd = dq * 16 + q * 4;
        lt[dd + 0][jr] = f2bf(vv.x);
        lt[dd + 1][jr] = f2bf(vv.y);
        lt[dd + 2][jr] = f2bf(vv.z);
        lt[dd + 3][jr] = f2bf(vv.w);
    }
    __syncthreads();
    int d = t >> 2;
    int jb = (t & 3) * 16;
    u16* dst = xlT + ((long)b * HIDDEN + d0 + d) * CHUNK + j0 + jb;
    uint4 w0 = *(const uint4*)&lt[d][jb];
    uint4 w1 = *(const uint4*)&lt[d][jb + 8];
    *(uint4*)dst = w0;
    *((uint4*)(dst + 8)) = w1;
}

// ---- C[b] = P[b] @ xlT[b]^T, scattered: out[b, hmap(i), n] = C[i][n] ----
// 128x128 tile, 4 waves, BK=64, DOUBLE-BUFFERED global_load_lds(16B) staging
// in recipe order (stage next || compute cur, one barrier/iter).
// XOR-swizzled LDS (slot = row*8 + (kb ^ (row&7))) on stage-src and read (rule 21).
// Also fuses the out-tail zeroing (96 MiB) into the kernel head when zflag!=0:
// stores retire at L2, writeback overlaps the compute phase.
__global__ __launch_bounds__(256) void gemm_scatter(const u16* __restrict__ P,
                                                    const u16* __restrict__ xlT,
                                                    float* __restrict__ out,
                                                    int zflag) {
    __shared__ u16 As[2][128 * 64];
    __shared__ u16 Bs[2][128 * 64];
    int blk = blockIdx.x;
    int b = blk >> 8;
    int tl = blk & 255;
    int ti = tl >> 4, tj = tl & 15;
    const int i0 = ti << 7, n0 = tj << 7;
    const u16* A = P + (long)b * CHUNK * CHUNK;
    const u16* B = xlT + (long)b * HIDDEN * CHUNK;
    int t = threadIdx.x, w = t >> 6, lane = t & 63;
    int wr = w >> 1, wc = w & 1;
    int srow = lane >> 3;              // row within 8-row stage segment
    int skb = (lane & 7) ^ srow;       // logical kb this lane fetches (inverse swizzle)

    // ---- fused tail zero: 512 blocks x 12288 float4 = 96 MiB ----
    if (zflag) {
        const int span = (SEQ - CHUNK) * (HIDDEN / 4);          // 3,145,728
        const long base0 = (long)CHUNK * (HIDDEN / 4);          // batch0 tail
        const long base1 = (long)(SEQ + CHUNK) * (HIDDEN / 4);  // batch1 tail
        float4* o4 = (float4*)out;
        const float4 z4 = make_float4(0.f, 0.f, 0.f, 0.f);
#pragma unroll
        for (int q = 0; q < 48; ++q) {
            int idx = blk * 12288 + q * 256 + t;
            int bb = idx >= span;
            int off = idx - (bb ? span : 0);
            o4[(bb ? base1 : base0) + off] = z4;
        }
    }

    f32x4 z = {0.f, 0.f, 0.f, 0.f};
    f32x4 acc[4][4];
#pragma unroll
    for (int m = 0; m < 4; ++m)
#pragma unroll
        for (int n = 0; n < 4; ++n) acc[m][n] = z;

    auto stage = [&](int pb, int k0) {
#pragma unroll
        for (int seg = 0; seg < 4; ++seg) {
            int q = (w << 2) + seg;         // stage instruction id 0..15
            int grow = (q << 3) + srow;     // tile row 0..127
            const u16* ga = A + (long)(i0 + grow) * CHUNK + k0 + (skb << 3);
            const u16* gb = B + (long)(n0 + grow) * CHUNK + k0 + (skb << 3);
            __builtin_amdgcn_global_load_lds(
                (const __attribute__((address_space(1))) void*)ga,
                (__attribute__((address_space(3))) void*)(&As[pb][q << 9]), 16, 0, 0);
            __builtin_amdgcn_global_load_lds(
                (const __attribute__((address_space(1))) void*)gb,
                (__attribute__((address_space(3))) void*)(&Bs[pb][q << 9]), 16, 0, 0);
        }
    };

    stage(0, 0);
    __syncthreads();  // buf0 ready (vmcnt(0) implied)

    const int NT = CHUNK / 64;  // 32
    for (int it = 0; it < NT; ++it) {
        int cur = it & 1;
        if (it + 1 < NT) stage(cur ^ 1, (it + 1) << 6);  // overlap with compute below
#pragma unroll
        for (int ks = 0; ks < 2; ++ks) {
            int kb = (ks << 2) + (lane >> 4);
            bf16x8 fa[4], fb[4];
#pragma unroll
            for (int m = 0; m < 4; ++m) {
                int row = (wr << 6) + (m << 4) + (lane & 15);
                int phys = (row << 3) + (kb ^ (row & 7));
                fa[m] = *(const bf16x8*)(&As[cur][phys << 3]);
            }
#pragma unroll
            for (int n = 0; n < 4; ++n) {
                int row = (wc << 6) + (n << 4) + (lane & 15);
                int phys = (row << 3) + (kb ^ (row & 7));
                fb[n] = *(const bf16x8*)(&Bs[cur][phys << 3]);
            }
#pragma unroll
            for (int m = 0; m < 4; ++m)
#pragma unroll
                for (int n = 0; n < 4; ++n)
                    acc[m][n] = __builtin_amdgcn_mfma_f32_16x16x32_bf16(
                        fa[m], fb[n], acc[m][n], 0, 0, 0);
        }
        __syncthreads();  // next buf ready; all reads of cur done before restage
    }

    // epilogue: C/D layout col=lane&15, row=(lane>>4)*4+r  [m89]
    int cr = (lane >> 4) << 2;
    int cc = lane & 15;
#pragma unroll
    for (int m = 0; m < 4; ++m) {
#pragma unroll
        for (int r = 0; r < 4; ++r) {
            int i = i0 + (wr << 6) + (m << 4) + cr + r;
            int orow = hmap(i);  // scatter row (stays < 2048)
            float* op = out + ((long)b * SEQ + orow) * HIDDEN + n0 + (wc << 6) + cc;
#pragma unroll
            for (int n = 0; n < 4; ++n) op[n << 4] = acc[m][n][r];
        }
    }
}

extern "C" void kernel_launch(void* const* d_in, const int* in_sizes, int n_in,
                              void* d_out, int out_size, void* d_ws, size_t ws_size,
                              hipStream_t stream) {
    const float* x = (const float*)d_in[0];
    const float* scores = (const float*)d_in[1];
    float* out = (float*)d_out;

    const size_t elems = (size_t)BATCH * CHUNK * CHUNK;  // u16 elements per buffer
    u16 *Pp, *xlT;
    bool ws_ok = (ws_size >= 2 * elems * sizeof(u16));
    if (ws_ok) {
        Pp = (u16*)d_ws;
        xlT = (u16*)d_ws + elems;
    } else {
        // stash in out's zero-tail (batch-0 rows [2048,6144)); zero_tail runs last
        Pp = (u16*)(out + (size_t)CHUNK * HIDDEN);
        xlT = (u16*)(out + (size_t)2 * CHUNK * HIDDEN);
    }

    softmax_sum<<<BATCH * CHUNK, 256, 0, stream>>>(scores, Pp);
    gather_transpose<<<2048, 256, 0, stream>>>(x, xlT);
    gemm_scatter<<<BATCH * 256, 256, 0, stream>>>(Pp, xlT, out, ws_ok ? 1 : 0);
    if (!ws_ok)
        zero_tail<<<(BATCH * (SEQ - CHUNK) * (HIDDEN / 4)) / 256, 256, 0, stream>>>((float4*)out);
}